// Round 5
// baseline (109.333 us; speedup 1.0000x reference)
//
#include <hip/hip_runtime.h>

#define NUM_PTS 1024
#define NBATCH 128
#define THREADS 256
#define NCHUNK 8                          // q-chunks per direction
#define CHUNK_PTS (NUM_PTS / NCHUNK)      // 128
#define CHAMF_SCALE (1.0f / 1024.0f)
#define KLD_SCALE   (-0.5f * 0.1f / 32.0f)

// ws layout (floats):
//   [0, 2M)          partials [2][NCHUNK][NBATCH][NUM_PTS]  = 8 MB
//   [2M, 2M+768K)    SoA      [2 clouds][NBATCH][3][NUM_PTS] = 3 MB
#define WS_CHUNK_STRIDE (NBATCH * NUM_PTS)          // 131072
#define WS_DIR_STRIDE   (NCHUNK * WS_CHUNK_STRIDE)  // 1048576
#define SOA_OFF         (2 * WS_DIR_STRIDE)         // 2097152 floats
#define SOA_CLOUD       (NBATCH * 3 * NUM_PTS)      // 393216

typedef float f2 __attribute__((ext_vector_type(2)));

// Force packed fp32 (compiler never auto-forms these — R1 evidence).
__device__ __forceinline__ f2 pk_fma(f2 a, f2 b, f2 c) {
    f2 d;
    asm("v_pk_fma_f32 %0, %1, %2, %3" : "=v"(d) : "v"(a), "v"(b), "v"(c));
    return d;
}
__device__ __forceinline__ f2 pk_mul(f2 a, f2 b) {
    f2 d;
    asm("v_pk_mul_f32 %0, %1, %2" : "=v"(d) : "v"(a), "v"(b));
    return d;
}

// AoS [B,N,3] -> SoA [B][{x,y,z}][N] for both clouds. 256 blocks
// (cloud*128+b), 4 pts/thread: 3 float4 reads -> 3 float4 writes.
__global__ __launch_bounds__(THREADS) void transpose_kernel(
    const float* __restrict__ recon_x,
    const float* __restrict__ x,
    float* __restrict__ soa)
{
    const int cloud = blockIdx.x >> 7;          // 0 = x, 1 = recon
    const int b     = blockIdx.x & 127;
    const float4* __restrict__ src =
        (const float4*)((cloud == 0 ? x : recon_x) + (size_t)b * NUM_PTS * 3);
    float* __restrict__ dst = soa + cloud * SOA_CLOUD + b * 3 * NUM_PTS;

    const int t = threadIdx.x;                  // points 4t..4t+3
    const float4 A = src[3 * t + 0];
    const float4 B = src[3 * t + 1];
    const float4 C = src[3 * t + 2];
    ((float4*)(dst          ))[t] = make_float4(A.x, A.w, B.z, C.y);  // qx
    ((float4*)(dst + NUM_PTS))[t] = make_float4(A.y, B.x, B.w, C.z);  // qy
    ((float4*)(dst + 2*NUM_PTS))[t] = make_float4(A.z, B.y, C.x, C.w); // qz
}

// 2048 blocks: blockIdx = b*16 + dir*8 + chunk; 8 blocks/CU = 8 waves/SIMD.
// dir 0: rows=x, min over recon (ref loss_2); dir 1: rows=recon (loss_1).
// R=4 rows/thread as broadcast f2 pairs; q stream from SoA as float2 pairs
// (2 q-points per pk instruction, zero packing movs). Per 2 qpts:
// 3 pk(q2) + 12 pk_fma + 4 min3 = 19 insts / 8 evals. ~52 live VGPRs.
__global__ __launch_bounds__(THREADS, 8) void chamfer_part(
    const float* __restrict__ recon_x,
    const float* __restrict__ x,
    const float* __restrict__ soa,
    float* __restrict__ ws)
{
    const int b     = blockIdx.x >> 4;
    const int sub   = blockIdx.x & 15;
    const int dir   = sub >> 3;
    const int chunk = sub & 7;

    const float* rp = (dir == 0 ? x : recon_x) + (size_t)b * NUM_PTS * 3;
    const float* qs = soa + (dir == 0 ? 1 : 0) * SOA_CLOUD
                      + b * 3 * NUM_PTS + chunk * CHUNK_PTS;
    const f2* __restrict__ qx2 = (const f2*)(qs);
    const f2* __restrict__ qy2 = (const f2*)(qs + NUM_PTS);
    const f2* __restrict__ qz2 = (const f2*)(qs + 2 * NUM_PTS);

    // --- own 4 rows: -2*coord broadcast into both pk halves; keep r2
    f2 vx[4], vy[4], vz[4];
    float r2[4], m[4];
#pragma unroll
    for (int k = 0; k < 4; ++k) {
        const int r = threadIdx.x + 256 * k;
        const float px = rp[3 * r + 0];
        const float py = rp[3 * r + 1];
        const float pz = rp[3 * r + 2];
        r2[k] = fmaf(px, px, fmaf(py, py, pz * pz));
        const float sx = -2.0f * px, sy = -2.0f * py, sz = -2.0f * pz;
        vx[k] = (f2){sx, sx};
        vy[k] = (f2){sy, sy};
        vz[k] = (f2){sz, sz};
        m[k] = 1e30f;
    }

    // --- 64 pair-iters over the 128-point q-chunk
#pragma unroll 2
    for (int t = 0; t < CHUNK_PTS / 2; ++t) {
        const f2 qx = qx2[t];
        const f2 qy = qy2[t];
        const f2 qz = qz2[t];
        const f2 q2 = pk_fma(qx, qx, pk_fma(qy, qy, pk_mul(qz, qz)));
#pragma unroll
        for (int r = 0; r < 4; ++r) {
            // tt = q2 - 2 v.q for both q points of the pair
            const f2 tt = pk_fma(vx[r], qx,
                           pk_fma(vy[r], qy,
                           pk_fma(vz[r], qz, q2)));
            m[r] = fminf(fminf(m[r], tt.x), tt.y);   // v_min3_f32
        }
    }

    // --- store per-row partial (r2 hoisted out of the min)
    float* dst = ws + dir * WS_DIR_STRIDE + chunk * WS_CHUNK_STRIDE
                 + b * NUM_PTS;
#pragma unroll
    for (int k = 0; k < 4; ++k)
        dst[threadIdx.x + 256 * k] = r2[k] + m[k];   // coalesced
}

// Min-combine the 8 chunk partials per row, sum all rows, fold in KLD.
__global__ __launch_bounds__(THREADS) void reduce_kernel(
    const float* __restrict__ ws,
    const float* __restrict__ mu,
    const float* __restrict__ logvar,
    float* __restrict__ out)
{
    const int s   = blockIdx.x * THREADS + threadIdx.x;  // 0..262143
    const int dir = s >> 17;
    const int rem = s & 131071;                          // batch*1024 + row

    const float* p = ws + dir * WS_DIR_STRIDE + rem;
    float mn = p[0];
#pragma unroll
    for (int c = 1; c < NCHUNK; ++c)
        mn = fminf(mn, p[c * WS_CHUNK_STRIDE]);
    float v = mn * CHAMF_SCALE;

    if (blockIdx.x < 16) {                               // 16*256 = 4096 latents
        const int t = blockIdx.x * THREADS + threadIdx.x;
        const float lv = logvar[t];
        const float mm = mu[t];
        v += (1.0f + lv - mm * mm - expf(lv)) * KLD_SCALE;
    }

    for (int off = 32; off > 0; off >>= 1)
        v += __shfl_down(v, off, 64);

    __shared__ float red[THREADS / 64];
    const int lane = threadIdx.x & 63;
    const int wv   = threadIdx.x >> 6;
    if (lane == 0) red[wv] = v;
    __syncthreads();
    if (threadIdx.x == 0) {
        float sum = 0.f;
        for (int w = 0; w < THREADS / 64; ++w) sum += red[w];
        atomicAdd(out, sum);
    }
}

extern "C" void kernel_launch(void* const* d_in, const int* in_sizes, int n_in,
                              void* d_out, int out_size, void* d_ws, size_t ws_size,
                              hipStream_t stream) {
    const float* recon_x = (const float*)d_in[0];
    const float* x       = (const float*)d_in[1];
    const float* mu      = (const float*)d_in[2];
    const float* logvar  = (const float*)d_in[3];
    float* out = (float*)d_out;
    float* ws  = (float*)d_ws;            // needs 11 MB
    float* soa = ws + SOA_OFF;

    hipMemsetAsync(out, 0, sizeof(float), stream);

    transpose_kernel<<<2 * NBATCH, THREADS, 0, stream>>>(recon_x, x, soa);
    chamfer_part<<<NBATCH * 2 * NCHUNK, THREADS, 0, stream>>>(recon_x, x, soa, ws);
    reduce_kernel<<<1024, THREADS, 0, stream>>>(ws, mu, logvar, out);
}

// Round 6
// 103.947 us; speedup vs baseline: 1.0518x; 1.0518x over previous
//
#include <hip/hip_runtime.h>

#define NUM_PTS 1024
#define NBATCH 128
#define THREADS 256
#define NCHUNK 8                          // q-chunks per direction
#define CHUNK_PTS (NUM_PTS / NCHUNK)      // 128
#define CHAMF_SCALE (1.0f / 1024.0f)
#define KLD_SCALE   (-0.5f * 0.1f / 32.0f)

// ws: float [2][NCHUNK][NBATCH][NUM_PTS] row partials = 8 MB.
// Every slot written exactly once (no init needed).
#define WS_CHUNK_STRIDE (NBATCH * NUM_PTS)          // 131072
#define WS_DIR_STRIDE   (NCHUNK * WS_CHUNK_STRIDE)  // 1048576

// 2048 blocks: blockIdx = b*16 + dir*8 + chunk; 8 blocks/CU.
// dir 0: rows=x, min over recon (ref loss_2); dir 1: rows=recon (loss_1).
// The 128-pt q-chunk (1.5 KB AoS) is staged into LDS ONCE per block --
// global latency paid once, not per iteration (R3/R4 were latency-bound on
// the streamed q loads: instruction diets didn't move duration). Inner loop:
// wave-uniform ds_read_b128 (broadcast, conflict-free) + scalar fp32 VALU
// (pk fp32 is rate-neutral on gfx950: 157.3 TF spec = scalar rate).
__global__ __launch_bounds__(THREADS, 8) void chamfer_part(
    const float* __restrict__ recon_x,
    const float* __restrict__ x,
    float* __restrict__ ws)
{
    const int b     = blockIdx.x >> 4;
    const int sub   = blockIdx.x & 15;
    const int dir   = sub >> 3;
    const int chunk = sub & 7;

    const float* rp = (dir == 0 ? x : recon_x) + (size_t)b * NUM_PTS * 3;
    const float* qp = (dir == 0 ? recon_x : x) + (size_t)b * NUM_PTS * 3
                      + chunk * CHUNK_PTS * 3;   // 96 float4s, 16B-aligned

    // --- stage q-chunk AoS -> LDS SoA (one-time; threads 96..255 idle here)
    __shared__ float4 sq4[3][CHUNK_PTS / 4];     // [coord][pt/4]
    float* const sq = (float*)sq4;               // sqx[128] | sqy[128] | sqz[128]
    if (threadIdx.x < 96) {
        const float4 v = ((const float4*)qp)[threadIdx.x];
        const int base = 4 * threadIdx.x;        // flat float index in chunk
#pragma unroll
        for (int i = 0; i < 4; ++i) {
            const int f = base + i;              // = 3*pt + coord
            sq[(f % 3) * CHUNK_PTS + f / 3] = (&v.x)[i];
        }
    }

    // --- own 4 rows: keep -2*coord and r2 (r2 hoisted out of the min)
    float vx[4], vy[4], vz[4], r2[4], m[4];
#pragma unroll
    for (int k = 0; k < 4; ++k) {
        const int r = threadIdx.x + 256 * k;
        const float px = rp[3 * r + 0];
        const float py = rp[3 * r + 1];
        const float pz = rp[3 * r + 2];
        r2[k] = fmaf(px, px, fmaf(py, py, pz * pz));
        vx[k] = -2.0f * px;
        vy[k] = -2.0f * py;
        vz[k] = -2.0f * pz;
        m[k]  = 1e30f;
    }
    __syncthreads();

    // --- 32 iters x 4 qpts, all operands LDS-resident
#pragma unroll 4
    for (int t = 0; t < CHUNK_PTS / 4; ++t) {
        const float4 qx = sq4[0][t];
        const float4 qy = sq4[1][t];
        const float4 qz = sq4[2][t];
        float q2[4], d[4][4];
#pragma unroll
        for (int j = 0; j < 4; ++j) {
            const float ax = (&qx.x)[j], ay = (&qy.x)[j], az = (&qz.x)[j];
            q2[j] = fmaf(ax, ax, fmaf(ay, ay, az * az));
#pragma unroll
            for (int r = 0; r < 4; ++r)
                d[j][r] = fmaf(vx[r], ax,
                          fmaf(vy[r], ay,
                          fmaf(vz[r], az, q2[j])));
        }
#pragma unroll
        for (int r = 0; r < 4; ++r) {
            m[r] = fminf(fminf(m[r], d[0][r]), d[1][r]);   // v_min3_f32
            m[r] = fminf(fminf(m[r], d[2][r]), d[3][r]);
        }
    }

    // --- store per-row partials, coalesced
    float* dst = ws + dir * WS_DIR_STRIDE + chunk * WS_CHUNK_STRIDE
                 + b * NUM_PTS;
#pragma unroll
    for (int k = 0; k < 4; ++k)
        dst[threadIdx.x + 256 * k] = r2[k] + m[k];
}

// Min-combine the 8 chunk partials per row, sum all rows, fold in KLD.
__global__ __launch_bounds__(THREADS) void reduce_kernel(
    const float* __restrict__ ws,
    const float* __restrict__ mu,
    const float* __restrict__ logvar,
    float* __restrict__ out)
{
    const int s   = blockIdx.x * THREADS + threadIdx.x;  // 0..262143
    const int dir = s >> 17;
    const int rem = s & 131071;                          // batch*1024 + row

    const float* p = ws + dir * WS_DIR_STRIDE + rem;
    float mn = p[0];
#pragma unroll
    for (int c = 1; c < NCHUNK; ++c)
        mn = fminf(mn, p[c * WS_CHUNK_STRIDE]);
    float v = mn * CHAMF_SCALE;

    if (blockIdx.x < 16) {                               // 16*256 = 4096 latents
        const int t = blockIdx.x * THREADS + threadIdx.x;
        const float lv = logvar[t];
        const float mm = mu[t];
        v += (1.0f + lv - mm * mm - expf(lv)) * KLD_SCALE;
    }

    for (int off = 32; off > 0; off >>= 1)
        v += __shfl_down(v, off, 64);

    __shared__ float red[THREADS / 64];
    const int lane = threadIdx.x & 63;
    const int wv   = threadIdx.x >> 6;
    if (lane == 0) red[wv] = v;
    __syncthreads();
    if (threadIdx.x == 0) {
        float sum = 0.f;
        for (int w = 0; w < THREADS / 64; ++w) sum += red[w];
        atomicAdd(out, sum);
    }
}

extern "C" void kernel_launch(void* const* d_in, const int* in_sizes, int n_in,
                              void* d_out, int out_size, void* d_ws, size_t ws_size,
                              hipStream_t stream) {
    const float* recon_x = (const float*)d_in[0];
    const float* x       = (const float*)d_in[1];
    const float* mu      = (const float*)d_in[2];
    const float* logvar  = (const float*)d_in[3];
    float* out = (float*)d_out;
    float* ws  = (float*)d_ws;            // needs 8 MB

    hipMemsetAsync(out, 0, sizeof(float), stream);

    chamfer_part<<<NBATCH * 2 * NCHUNK, THREADS, 0, stream>>>(recon_x, x, ws);
    reduce_kernel<<<1024, THREADS, 0, stream>>>(ws, mu, logvar, out);
}

// Round 7
// 101.992 us; speedup vs baseline: 1.0720x; 1.0192x over previous
//
#include <hip/hip_runtime.h>

#define NUM_PTS 1024
#define NBATCH 128
#define BTHREADS 128                      // chamfer block size (2 waves)
#define THREADS 256                       // reduce block size
#define NCHUNK 8
#define CHUNK_PTS (NUM_PTS / NCHUNK)      // 128
#define CHAMF_SCALE (1.0f / 1024.0f)
#define KLD_SCALE   (-0.5f * 0.1f / 32.0f)

// ws: float [2][NCHUNK][NBATCH][NUM_PTS] row partials = 8 MB.
#define WS_CHUNK_STRIDE (NBATCH * NUM_PTS)          // 131072
#define WS_DIR_STRIDE   (NCHUNK * WS_CHUNK_STRIDE)  // 1048576

// 2048 blocks x 128 threads: blockIdx = b*16 + dir*8 + chunk; 8 blocks/CU =
// 16 waves/CU = 4 waves/SIMD. R=8 rows/thread halves per-CU LDS-pipe
// pressure vs R5's R=4 (R5: 37K LDS cyc/CU ~ parity with 35K VALU cyc/SIMD
// -- the broadcast ds_read costs per INSTRUCTION, not per byte). q2 is
// precomputed into LDS at staging, deleting it from the hot loop:
// per 4 qpts x 8 rows: 4 ds_read_b128 + 96 fma + 16 min3 = 3.5 VALU/eval.
__global__ __launch_bounds__(BTHREADS, 4) void chamfer_part(
    const float* __restrict__ recon_x,
    const float* __restrict__ x,
    float* __restrict__ ws)
{
    const int b     = blockIdx.x >> 4;
    const int sub   = blockIdx.x & 15;
    const int dir   = sub >> 3;
    const int chunk = sub & 7;

    const float* rp = (dir == 0 ? x : recon_x) + (size_t)b * NUM_PTS * 3;
    const float* qp = (dir == 0 ? recon_x : x) + (size_t)b * NUM_PTS * 3
                      + chunk * CHUNK_PTS * 3;

    // --- stage q-chunk: SoA planes {x, y, z, q2}, one point per thread
    __shared__ float sq[4][CHUNK_PTS];    // 2 KB
    {
        const int p = threadIdx.x;        // 128 threads = 128 points
        const float qx = qp[3 * p + 0];
        const float qy = qp[3 * p + 1];
        const float qz = qp[3 * p + 2];
        sq[0][p] = qx;
        sq[1][p] = qy;
        sq[2][p] = qz;
        sq[3][p] = fmaf(qx, qx, fmaf(qy, qy, qz * qz));
    }

    // --- own 8 rows: -2*coord and r2 (r2 hoisted out of the min)
    float vx[8], vy[8], vz[8], r2[8], m[8];
#pragma unroll
    for (int k = 0; k < 8; ++k) {
        const int r = threadIdx.x + BTHREADS * k;
        const float px = rp[3 * r + 0];
        const float py = rp[3 * r + 1];
        const float pz = rp[3 * r + 2];
        r2[k] = fmaf(px, px, fmaf(py, py, pz * pz));
        vx[k] = -2.0f * px;
        vy[k] = -2.0f * py;
        vz[k] = -2.0f * pz;
        m[k]  = 1e30f;
    }
    __syncthreads();

    // --- 32 iters x 4 qpts, operands LDS-resident (wave-uniform broadcast)
    const float4* __restrict__ sx4 = (const float4*)sq[0];
    const float4* __restrict__ sy4 = (const float4*)sq[1];
    const float4* __restrict__ sz4 = (const float4*)sq[2];
    const float4* __restrict__ s24 = (const float4*)sq[3];
#pragma unroll 2
    for (int t = 0; t < CHUNK_PTS / 4; ++t) {
        const float4 qx = sx4[t];
        const float4 qy = sy4[t];
        const float4 qz = sz4[t];
        const float4 q2 = s24[t];
#pragma unroll
        for (int jp = 0; jp < 2; ++jp) {          // q-points in pairs -> min3
            const int j0 = 2 * jp, j1 = 2 * jp + 1;
            const float ax0 = (&qx.x)[j0], ay0 = (&qy.x)[j0],
                        az0 = (&qz.x)[j0], aq0 = (&q2.x)[j0];
            const float ax1 = (&qx.x)[j1], ay1 = (&qy.x)[j1],
                        az1 = (&qz.x)[j1], aq1 = (&q2.x)[j1];
            float d0[8], d1[8];
#pragma unroll
            for (int r = 0; r < 8; ++r)
                d0[r] = fmaf(vx[r], ax0, fmaf(vy[r], ay0, fmaf(vz[r], az0, aq0)));
#pragma unroll
            for (int r = 0; r < 8; ++r)
                d1[r] = fmaf(vx[r], ax1, fmaf(vy[r], ay1, fmaf(vz[r], az1, aq1)));
#pragma unroll
            for (int r = 0; r < 8; ++r)
                m[r] = fminf(fminf(m[r], d0[r]), d1[r]);   // v_min3_f32
        }
    }

    // --- store per-row partials, coalesced
    float* dst = ws + dir * WS_DIR_STRIDE + chunk * WS_CHUNK_STRIDE
                 + b * NUM_PTS;
#pragma unroll
    for (int k = 0; k < 8; ++k)
        dst[threadIdx.x + BTHREADS * k] = r2[k] + m[k];
}

// Min-combine the 8 chunk partials per row, sum all rows, fold in KLD.
__global__ __launch_bounds__(THREADS) void reduce_kernel(
    const float* __restrict__ ws,
    const float* __restrict__ mu,
    const float* __restrict__ logvar,
    float* __restrict__ out)
{
    const int s   = blockIdx.x * THREADS + threadIdx.x;  // 0..262143
    const int dir = s >> 17;
    const int rem = s & 131071;                          // batch*1024 + row

    const float* p = ws + dir * WS_DIR_STRIDE + rem;
    float mn = p[0];
#pragma unroll
    for (int c = 1; c < NCHUNK; ++c)
        mn = fminf(mn, p[c * WS_CHUNK_STRIDE]);
    float v = mn * CHAMF_SCALE;

    if (blockIdx.x < 16) {                               // 16*256 = 4096 latents
        const int t = blockIdx.x * THREADS + threadIdx.x;
        const float lv = logvar[t];
        const float mm = mu[t];
        v += (1.0f + lv - mm * mm - expf(lv)) * KLD_SCALE;
    }

    for (int off = 32; off > 0; off >>= 1)
        v += __shfl_down(v, off, 64);

    __shared__ float red[THREADS / 64];
    const int lane = threadIdx.x & 63;
    const int wv   = threadIdx.x >> 6;
    if (lane == 0) red[wv] = v;
    __syncthreads();
    if (threadIdx.x == 0) {
        float sum = 0.f;
        for (int w = 0; w < THREADS / 64; ++w) sum += red[w];
        atomicAdd(out, sum);
    }
}

extern "C" void kernel_launch(void* const* d_in, const int* in_sizes, int n_in,
                              void* d_out, int out_size, void* d_ws, size_t ws_size,
                              hipStream_t stream) {
    const float* recon_x = (const float*)d_in[0];
    const float* x       = (const float*)d_in[1];
    const float* mu      = (const float*)d_in[2];
    const float* logvar  = (const float*)d_in[3];
    float* out = (float*)d_out;
    float* ws  = (float*)d_ws;            // needs 8 MB

    hipMemsetAsync(out, 0, sizeof(float), stream);

    chamfer_part<<<NBATCH * 2 * NCHUNK, BTHREADS, 0, stream>>>(recon_x, x, ws);
    reduce_kernel<<<1024, THREADS, 0, stream>>>(ws, mu, logvar, out);
}

// Round 8
// 91.938 us; speedup vs baseline: 1.1892x; 1.1094x over previous
//
#include <hip/hip_runtime.h>

#define NUM_PTS 1024
#define NBATCH 128
#define BTHREADS 128                      // chamfer block size (2 waves)
#define THREADS 256                       // reduce block size
#define NCHUNK 8
#define CHUNK_PTS (NUM_PTS / NCHUNK)      // 128
#define CHAMF_SCALE (1.0f / 1024.0f)
#define KLD_SCALE   (-0.5f * 0.1f / 32.0f)

// ws: float [2][NCHUNK][NBATCH][NUM_PTS] row partials = 8 MB.
#define WS_CHUNK_STRIDE (NBATCH * NUM_PTS)          // 131072
#define WS_DIR_STRIDE   (NCHUNK * WS_CHUNK_STRIDE)  // 1048576

// 2048 blocks x 128 threads: blockIdx = b*16 + dir*8 + chunk; 8 blocks/CU =
// 16 waves/CU = 4 waves/SIMD. R=8 CONTIGUOUS rows/thread: row prologue is
// 6 x global_load_dwordx4 (was 24 scalar strided loads), ws epilogue is
// 2 x float4 stores (was 8 scalar). Inner loop unchanged from R6 (balanced:
// per CU-iter LDS 768 cyc vs VALU 896 cyc/SIMD): 4 ds_read_b128 + 112 VALU
// per thread per 4 q-points, q2 pre-staged in the 4th LDS plane.
__global__ __launch_bounds__(BTHREADS, 4) void chamfer_part(
    const float* __restrict__ recon_x,
    const float* __restrict__ x,
    float* __restrict__ ws)
{
    const int b     = blockIdx.x >> 4;
    const int sub   = blockIdx.x & 15;
    const int dir   = sub >> 3;
    const int chunk = sub & 7;

    const float* rp = (dir == 0 ? x : recon_x) + (size_t)b * NUM_PTS * 3;
    const float* qp = (dir == 0 ? recon_x : x) + (size_t)b * NUM_PTS * 3
                      + chunk * CHUNK_PTS * 3;

    // --- stage q-chunk: SoA planes {x, y, z, q2}, one point per thread
    __shared__ float sq[4][CHUNK_PTS];    // 2 KB
    {
        const int p = threadIdx.x;
        const float qx = qp[3 * p + 0];
        const float qy = qp[3 * p + 1];
        const float qz = qp[3 * p + 2];
        sq[0][p] = qx;
        sq[1][p] = qy;
        sq[2][p] = qz;
        sq[3][p] = fmaf(qx, qx, fmaf(qy, qy, qz * qz));
    }

    // --- own 8 contiguous rows (8t..8t+7): 6 coalesced float4 loads
    float buf[24];
    {
        const float4* __restrict__ src = (const float4*)(rp + 24 * threadIdx.x);
        float4* bp = (float4*)buf;
#pragma unroll
        for (int i = 0; i < 6; ++i) bp[i] = src[i];
    }
    float vx[8], vy[8], vz[8], r2[8], m[8];
#pragma unroll
    for (int k = 0; k < 8; ++k) {
        const float px = buf[3 * k + 0];
        const float py = buf[3 * k + 1];
        const float pz = buf[3 * k + 2];
        r2[k] = fmaf(px, px, fmaf(py, py, pz * pz));
        vx[k] = -2.0f * px;
        vy[k] = -2.0f * py;
        vz[k] = -2.0f * pz;
        m[k]  = 1e30f;
    }
    __syncthreads();

    // --- 32 iters x 4 qpts, operands LDS-resident (wave-uniform broadcast)
    const float4* __restrict__ sx4 = (const float4*)sq[0];
    const float4* __restrict__ sy4 = (const float4*)sq[1];
    const float4* __restrict__ sz4 = (const float4*)sq[2];
    const float4* __restrict__ s24 = (const float4*)sq[3];
#pragma unroll 2
    for (int t = 0; t < CHUNK_PTS / 4; ++t) {
        const float4 qx = sx4[t];
        const float4 qy = sy4[t];
        const float4 qz = sz4[t];
        const float4 q2 = s24[t];
#pragma unroll
        for (int jp = 0; jp < 2; ++jp) {          // q-points in pairs -> min3
            const int j0 = 2 * jp, j1 = 2 * jp + 1;
            const float ax0 = (&qx.x)[j0], ay0 = (&qy.x)[j0],
                        az0 = (&qz.x)[j0], aq0 = (&q2.x)[j0];
            const float ax1 = (&qx.x)[j1], ay1 = (&qy.x)[j1],
                        az1 = (&qz.x)[j1], aq1 = (&q2.x)[j1];
            float d0[8], d1[8];
#pragma unroll
            for (int r = 0; r < 8; ++r)
                d0[r] = fmaf(vx[r], ax0, fmaf(vy[r], ay0, fmaf(vz[r], az0, aq0)));
#pragma unroll
            for (int r = 0; r < 8; ++r)
                d1[r] = fmaf(vx[r], ax1, fmaf(vy[r], ay1, fmaf(vz[r], az1, aq1)));
#pragma unroll
            for (int r = 0; r < 8; ++r)
                m[r] = fminf(fminf(m[r], d0[r]), d1[r]);   // v_min3_f32
        }
    }

    // --- store 8 contiguous per-row partials as 2 float4s (coalesced)
    float4* dst = (float4*)(ws + dir * WS_DIR_STRIDE + chunk * WS_CHUNK_STRIDE
                            + b * NUM_PTS + 8 * threadIdx.x);
    dst[0] = make_float4(r2[0] + m[0], r2[1] + m[1], r2[2] + m[2], r2[3] + m[3]);
    dst[1] = make_float4(r2[4] + m[4], r2[5] + m[5], r2[6] + m[6], r2[7] + m[7]);
}

// Min-combine the 8 chunk partials per row (4 rows/thread via float4),
// sum all rows, fold in KLD. 256 blocks x 256 threads.
__global__ __launch_bounds__(THREADS) void reduce_kernel(
    const float* __restrict__ ws,
    const float* __restrict__ mu,
    const float* __restrict__ logvar,
    float* __restrict__ out)
{
    const int gid  = blockIdx.x * THREADS + threadIdx.x;  // 0..65535
    const int base = gid * 4;                             // flat slot
    const int dir  = base >> 17;
    const int rem  = base & 131071;                       // batch*1024 + row

    const float4* p = (const float4*)(ws + dir * WS_DIR_STRIDE + rem);
    float4 mn = p[0];
#pragma unroll
    for (int c = 1; c < NCHUNK; ++c) {
        const float4 q = p[c * (WS_CHUNK_STRIDE / 4)];
        mn.x = fminf(mn.x, q.x);
        mn.y = fminf(mn.y, q.y);
        mn.z = fminf(mn.z, q.z);
        mn.w = fminf(mn.w, q.w);
    }
    float v = (mn.x + mn.y + mn.z + mn.w) * CHAMF_SCALE;

    if (blockIdx.x < 16) {                                // 16*256 = 4096 latents
        const int t = blockIdx.x * THREADS + threadIdx.x;
        const float lv = logvar[t];
        const float mm = mu[t];
        v += (1.0f + lv - mm * mm - expf(lv)) * KLD_SCALE;
    }

    for (int off = 32; off > 0; off >>= 1)
        v += __shfl_down(v, off, 64);

    __shared__ float red[THREADS / 64];
    const int lane = threadIdx.x & 63;
    const int wv   = threadIdx.x >> 6;
    if (lane == 0) red[wv] = v;
    __syncthreads();
    if (threadIdx.x == 0) {
        float sum = 0.f;
        for (int w = 0; w < THREADS / 64; ++w) sum += red[w];
        atomicAdd(out, sum);
    }
}

extern "C" void kernel_launch(void* const* d_in, const int* in_sizes, int n_in,
                              void* d_out, int out_size, void* d_ws, size_t ws_size,
                              hipStream_t stream) {
    const float* recon_x = (const float*)d_in[0];
    const float* x       = (const float*)d_in[1];
    const float* mu      = (const float*)d_in[2];
    const float* logvar  = (const float*)d_in[3];
    float* out = (float*)d_out;
    float* ws  = (float*)d_ws;            // needs 8 MB

    hipMemsetAsync(out, 0, sizeof(float), stream);

    chamfer_part<<<NBATCH * 2 * NCHUNK, BTHREADS, 0, stream>>>(recon_x, x, ws);
    reduce_kernel<<<256, THREADS, 0, stream>>>(ws, mu, logvar, out);
}